// Round 12
// baseline (258.864 us; speedup 1.0000x reference)
//
#include <hip/hip_runtime.h>

#define D 133
#define DPB 160       // bf16 row stride (ushorts): 320 B; 5 K-steps of 32 for MFMA
#define NCGB 17       // bf16 column groups of 8 (covers 136)
#define NGRAPH 256
#define KS 168        // W^T global row stride in ushorts (16B-aligned rows)
#define LSTR 168      // LDS A-tile row stride in ushorts (336 B -> spread banks)
#define NT 9          // N-tiles of 16 (covers 144 >= 133)
#define CAP 64        // fixed CSR bucket capacity (P(Poisson(16) > 64) ~ 1e-19)
#define EU 8          // edges per thread in fill

typedef short short8 __attribute__((ext_vector_type(8)));
typedef float float4v __attribute__((ext_vector_type(4)));

__device__ __forceinline__ unsigned short f2bf(float x) {   // RNE
    unsigned int u = __float_as_uint(x);
    u += 0x7fffu + ((u >> 16) & 1u);
    return (unsigned short)(u >> 16);
}

__device__ __forceinline__ void cvt8(uint4 v, float* f) {
    f[0] = __uint_as_float(v.x << 16);
    f[1] = __uint_as_float(v.x & 0xffff0000u);
    f[2] = __uint_as_float(v.y << 16);
    f[3] = __uint_as_float(v.y & 0xffff0000u);
    f[4] = __uint_as_float(v.z << 16);
    f[5] = __uint_as_float(v.z & 0xffff0000u);
    f[6] = __uint_as_float(v.w << 16);
    f[7] = __uint_as_float(v.w & 0xffff0000u);
}

// ---------- prep: wt1 | wt2 | cnt-zero | gstart ----------
__global__ __launch_bounds__(256) void k_wt(const float* __restrict__ W1,
                                            unsigned short* __restrict__ WT1,
                                            const float* __restrict__ W2,
                                            unsigned short* __restrict__ WT2,
                                            int* __restrict__ cnt,
                                            const int* __restrict__ batch,
                                            int* __restrict__ gstart,
                                            int N, int wtB, int czB) {
    int bid = blockIdx.x, t = threadIdx.x;
    if (bid < 2 * wtB) {
        const float* W = (bid < wtB) ? W1 : W2;
        unsigned short* WT = (bid < wtB) ? WT1 : WT2;
        int lb = (bid < wtB) ? bid : bid - wtB;
        int i = lb * 256 + t;
        if (i < 144 * KS) {
            int n = i / KS, k = i - n * KS;
            WT[i] = (n < D && k < D) ? f2bf(W[(size_t)k * D + n]) : (unsigned short)0;
        }
        return;
    }
    bid -= 2 * wtB;
    if (bid < czB) {
        int i = bid * 256 + t;
        if (i < N) cnt[i] = 0;
        return;
    }
    bid -= czB;
    {
        int g = bid * 256 + t;
        if (g > NGRAPH) return;
        int lo = 0, hi = N;
        while (lo < hi) {
            int mid = (lo + hi) >> 1;
            if (batch[mid] < g) lo = mid + 1; else hi = mid;
        }
        gstart[g] = lo;
    }
}

// ---------- fused: XCD-range-partitioned edge fill + layer-1 MFMA ----------
// Fill blocks (bid < nfill): group g = bid & 7 handles dst range [g*N/8,(g+1)*N/8);
// chunk = bid >> 3 selects the edge window. %8 residue aligns group -> XCD so
// earr/cnt lines are written by one XCD only. mm1 blocks appended after.
__global__ __launch_bounds__(256, 2) void k_big(const float* __restrict__ X,
                                                const unsigned short* __restrict__ WTg,
                                                unsigned short* __restrict__ Y,
                                                const int* __restrict__ src,
                                                const int* __restrict__ dst,
                                                int* __restrict__ cnt,
                                                unsigned short* __restrict__ earr,
                                                int N, int E, int mt, int nfill) {
    int bid = blockIdx.x, t = threadIdx.x;
    if (bid < nfill) {                           // --- fill: range-filtered scan ---
        int g = bid & 7;
        int chunk = bid >> 3;
        int rlo = g * (N >> 3);
        int rhi = (g == 7) ? N : rlo + (N >> 3);
        int i0 = (chunk * 256 + t) * EU;
        if (i0 >= E) return;
        int dv[EU];
        if (i0 + EU <= E) {
            int4 a = *(const int4*)(dst + i0);
            int4 b = *(const int4*)(dst + i0 + 4);
            dv[0]=a.x; dv[1]=a.y; dv[2]=a.z; dv[3]=a.w;
            dv[4]=b.x; dv[5]=b.y; dv[6]=b.z; dv[7]=b.w;
        } else {
            #pragma unroll
            for (int j = 0; j < EU; ++j) dv[j] = (i0 + j < E) ? dst[i0 + j] : -1;
        }
        #pragma unroll
        for (int j = 0; j < EU; ++j) {
            int dnode = dv[j];
            if (dnode >= rlo && dnode < rhi) {
                int s = src[i0 + j];
                int slot = atomicAdd(&cnt[dnode], 1);
                if (slot < CAP) earr[(size_t)dnode * CAP + slot] = (unsigned short)s;
            }
        }
        return;
    }
    bid -= nfill;
    // --- mm1: one 16-row tile per wave, fp32 X, cvt in-register ---
    int wave = t >> 6, lane = t & 63;
    int ln16 = lane & 15, quad = lane >> 4;
    int tile = bid * 4 + wave;
    if (tile >= mt) return;
    int row0 = tile * 16;
    int ra = row0 + ln16; if (ra > N - 1) ra = N - 1;
    const float* Xr = X + (size_t)ra * D;
    const unsigned short* Wr = WTg + (size_t)ln16 * KS + quad * 8;

    float4v acc[NT];
    #pragma unroll
    for (int n = 0; n < NT; ++n) acc[n] = {0.f, 0.f, 0.f, 0.f};

    #pragma unroll
    for (int kk = 0; kk < 5; ++kk) {
        int cbase = kk * 32 + quad * 8;
        short8 a;
        if (kk < 4) {
            #pragma unroll
            for (int j = 0; j < 8; ++j) a[j] = (short)f2bf(Xr[cbase + j]);
        } else {
            #pragma unroll
            for (int j = 0; j < 8; ++j) {
                int c = cbase + j;
                a[j] = (short)((c < D) ? f2bf(Xr[c]) : 0);
            }
        }
        #pragma unroll
        for (int n = 0; n < NT; ++n) {
            short8 b = *(const short8*)(Wr + n * 16 * KS + kk * 32);
            acc[n] = __builtin_amdgcn_mfma_f32_16x16x32_bf16(a, b, acc[n], 0, 0, 0);
        }
    }
    #pragma unroll
    for (int r = 0; r < 4; ++r) {
        int row = row0 + quad * 4 + r;
        if (row < N) {
            unsigned short* Yr = Y + (size_t)row * DPB + ln16;
            #pragma unroll
            for (int n = 0; n < NT; ++n) Yr[n * 16] = f2bf(acc[n][r]);
        }
    }
}

// ---------- fused agg1 (gather+norm+bias+relu -> LDS) + mm2 (LDS -> H2) ----------
__global__ __launch_bounds__(320, 2) void k_aggmm(const unsigned short* __restrict__ H,
                                                  const float* __restrict__ bias,
                                                  const int* __restrict__ cnt,
                                                  const unsigned short* __restrict__ earr,
                                                  const unsigned short* __restrict__ WTg,
                                                  unsigned short* __restrict__ Y, int N) {
    __shared__ unsigned short T[16 * LSTR];   // 5.25 KB bf16 A-tile
    int t = threadIdx.x;
    int row0 = blockIdx.x * 16;
    if (t < 272) {                            // --- agg task: node row0+l, col-group cg ---
        int l = t / NCGB;
        int cg = t - l * NCGB;
        int node = row0 + l;
        if (node >= N) node = N - 1;
        int c = cg << 3;
        int degraw = cnt[node];
        float di = rsqrtf((float)(degraw + 1));
        float acc[8], f[8];
        uint4 hv = *(const uint4*)(H + (size_t)node * DPB + c);
        cvt8(hv, f);
        #pragma unroll
        for (int j = 0; j < 8; ++j) acc[j] = di * f[j];
        int deg = degraw > CAP ? CAP : degraw;
        const unsigned short* ep = earr + (size_t)node * CAP;
        int e = 0;
        for (; e + 4 <= deg; e += 4) {
            int s0 = ep[e], s1 = ep[e+1], s2 = ep[e+2], s3 = ep[e+3];
            float w0 = rsqrtf((float)(cnt[s0] + 1));
            float w1 = rsqrtf((float)(cnt[s1] + 1));
            float w2 = rsqrtf((float)(cnt[s2] + 1));
            float w3 = rsqrtf((float)(cnt[s3] + 1));
            uint4 v0 = *(const uint4*)(H + (size_t)s0 * DPB + c);
            uint4 v1 = *(const uint4*)(H + (size_t)s1 * DPB + c);
            uint4 v2 = *(const uint4*)(H + (size_t)s2 * DPB + c);
            uint4 v3 = *(const uint4*)(H + (size_t)s3 * DPB + c);
            cvt8(v0, f);
            #pragma unroll
            for (int j = 0; j < 8; ++j) acc[j] = fmaf(w0, f[j], acc[j]);
            cvt8(v1, f);
            #pragma unroll
            for (int j = 0; j < 8; ++j) acc[j] = fmaf(w1, f[j], acc[j]);
            cvt8(v2, f);
            #pragma unroll
            for (int j = 0; j < 8; ++j) acc[j] = fmaf(w2, f[j], acc[j]);
            cvt8(v3, f);
            #pragma unroll
            for (int j = 0; j < 8; ++j) acc[j] = fmaf(w3, f[j], acc[j]);
        }
        for (; e < deg; ++e) {
            int s = ep[e];
            float wv = rsqrtf((float)(cnt[s] + 1));
            uint4 v = *(const uint4*)(H + (size_t)s * DPB + c);
            cvt8(v, f);
            #pragma unroll
            for (int j = 0; j < 8; ++j) acc[j] = fmaf(wv, f[j], acc[j]);
        }
        float b[8];
        #pragma unroll
        for (int j = 0; j < 8; ++j) b[j] = (c + j < D) ? bias[c + j] : 0.f;
        unsigned int p[4];
        #pragma unroll
        for (int j = 0; j < 4; ++j) {
            float lo = fmaxf(fmaf(di, acc[2*j],   b[2*j]),   0.f);
            float hi = fmaxf(fmaf(di, acc[2*j+1], b[2*j+1]), 0.f);
            p[j] = (unsigned int)f2bf(lo) | ((unsigned int)f2bf(hi) << 16);
        }
        uint4 pk = {p[0], p[1], p[2], p[3]};
        *(uint4*)(T + l * LSTR + c) = pk;
    } else {                                  // --- zero LDS K-pads 136..159 ---
        int k = t - 272;
        int l = k / 3, seg = k - l * 3;
        uint4 z = {0u, 0u, 0u, 0u};
        *(uint4*)(T + l * LSTR + 136 + seg * 8) = z;
    }
    __syncthreads();

    // --- mm2: 5 waves split the 9 N-tiles; A-frags from LDS ---
    int wave = t >> 6, lane = t & 63;
    int ln16 = lane & 15, quad = lane >> 4;
    const unsigned short* Ar = T + ln16 * LSTR + quad * 8;
    const unsigned short* Wr = WTg + (size_t)ln16 * KS + quad * 8;
    for (int n = wave; n < NT; n += 5) {
        float4v acc2 = {0.f, 0.f, 0.f, 0.f};
        #pragma unroll
        for (int kk = 0; kk < 5; ++kk) {
            short8 a = *(const short8*)(Ar + kk * 32);
            short8 b = *(const short8*)(Wr + n * 16 * KS + kk * 32);
            acc2 = __builtin_amdgcn_mfma_f32_16x16x32_bf16(a, b, acc2, 0, 0, 0);
        }
        #pragma unroll
        for (int r = 0; r < 4; ++r) {
            int row = row0 + quad * 4 + r;
            if (row < N) Y[(size_t)row * DPB + n * 16 + ln16] = f2bf(acc2[r]);
        }
    }
}

// ---------- agg2: gather+norm+bias+relu; bf16 out (pool ignores pads) ----------
__global__ __launch_bounds__(256) void k_agg2(const unsigned short* __restrict__ H,
                                              const float* __restrict__ bias,
                                              const int* __restrict__ cnt,
                                              const unsigned short* __restrict__ earr,
                                              unsigned short* __restrict__ outb, int N) {
    int idx = blockIdx.x * 256 + threadIdx.x;
    if (idx >= N * NCGB) return;
    int node = idx / NCGB;
    int cg = idx - node * NCGB;
    int c = cg << 3;
    int degraw = cnt[node];
    float di = rsqrtf((float)(degraw + 1));
    float acc[8], f[8];
    uint4 hv = *(const uint4*)(H + (size_t)node * DPB + c);
    cvt8(hv, f);
    #pragma unroll
    for (int j = 0; j < 8; ++j) acc[j] = di * f[j];
    int deg = degraw > CAP ? CAP : degraw;
    const unsigned short* ep = earr + (size_t)node * CAP;
    int e = 0;
    for (; e + 4 <= deg; e += 4) {
        int s0 = ep[e], s1 = ep[e+1], s2 = ep[e+2], s3 = ep[e+3];
        float w0 = rsqrtf((float)(cnt[s0] + 1));
        float w1 = rsqrtf((float)(cnt[s1] + 1));
        float w2 = rsqrtf((float)(cnt[s2] + 1));
        float w3 = rsqrtf((float)(cnt[s3] + 1));
        uint4 v0 = *(const uint4*)(H + (size_t)s0 * DPB + c);
        uint4 v1 = *(const uint4*)(H + (size_t)s1 * DPB + c);
        uint4 v2 = *(const uint4*)(H + (size_t)s2 * DPB + c);
        uint4 v3 = *(const uint4*)(H + (size_t)s3 * DPB + c);
        cvt8(v0, f);
        #pragma unroll
        for (int j = 0; j < 8; ++j) acc[j] = fmaf(w0, f[j], acc[j]);
        cvt8(v1, f);
        #pragma unroll
        for (int j = 0; j < 8; ++j) acc[j] = fmaf(w1, f[j], acc[j]);
        cvt8(v2, f);
        #pragma unroll
        for (int j = 0; j < 8; ++j) acc[j] = fmaf(w2, f[j], acc[j]);
        cvt8(v3, f);
        #pragma unroll
        for (int j = 0; j < 8; ++j) acc[j] = fmaf(w3, f[j], acc[j]);
    }
    for (; e < deg; ++e) {
        int s = ep[e];
        float wv = rsqrtf((float)(cnt[s] + 1));
        uint4 v = *(const uint4*)(H + (size_t)s * DPB + c);
        cvt8(v, f);
        #pragma unroll
        for (int j = 0; j < 8; ++j) acc[j] = fmaf(wv, f[j], acc[j]);
    }
    float b[8];
    #pragma unroll
    for (int j = 0; j < 8; ++j) b[j] = (c + j < D) ? bias[c + j] : 0.f;
    unsigned int p[4];
    #pragma unroll
    for (int j = 0; j < 4; ++j) {
        float lo = fmaxf(fmaf(di, acc[2*j],   b[2*j]),   0.f);
        float hi = fmaxf(fmaf(di, acc[2*j+1], b[2*j+1]), 0.f);
        p[j] = (unsigned int)f2bf(lo) | ((unsigned int)f2bf(hi) << 16);
    }
    uint4 pk = {p[0], p[1], p[2], p[3]};
    *(uint4*)(outb + (size_t)node * DPB + c) = pk;
}

// ---------- per-graph mean pool: one block per (graph, col-group of 8) ----------
__global__ __launch_bounds__(256) void k_pool(const unsigned short* __restrict__ H,
                                              const int* __restrict__ gstart,
                                              float* __restrict__ out) {
    int g = blockIdx.x / NCGB;
    int cg = blockIdx.x - g * NCGB;
    int c = cg << 3;
    int t = threadIdx.x;
    int s = gstart[g], e = gstart[g + 1];
    float acc[8], f[8];
    #pragma unroll
    for (int j = 0; j < 8; ++j) acc[j] = 0.f;
    for (int i = s + t; i < e; i += 256) {
        uint4 v = *(const uint4*)(H + (size_t)i * DPB + c);
        cvt8(v, f);
        #pragma unroll
        for (int j = 0; j < 8; ++j) acc[j] += f[j];
    }
    #pragma unroll
    for (int off = 32; off >= 1; off >>= 1) {
        #pragma unroll
        for (int j = 0; j < 8; ++j) acc[j] += __shfl_down(acc[j], off, 64);
    }
    __shared__ float part[4][8];
    int wave = t >> 6, lane = t & 63;
    if (lane == 0) {
        #pragma unroll
        for (int j = 0; j < 8; ++j) part[wave][j] = acc[j];
    }
    __syncthreads();
    if (t < 8) {
        int col = c + t;
        if (col < D) {
            float v = part[0][t] + part[1][t] + part[2][t] + part[3][t];
            float n = (float)(e - s);
            out[(size_t)g * D + col] = v / fmaxf(n, 1.f);
        }
    }
}

extern "C" void kernel_launch(void* const* d_in, const int* in_sizes, int n_in,
                              void* d_out, int out_size, void* d_ws, size_t ws_size,
                              hipStream_t stream) {
    const float* x   = (const float*)d_in[0];
    const int* ei    = (const int*)d_in[1];
    const int* batch = (const int*)d_in[2];
    const float* W1  = (const float*)d_in[3];
    const float* b1  = (const float*)d_in[4];
    const float* W2  = (const float*)d_in[5];
    const float* b2  = (const float*)d_in[6];
    float* out = (float*)d_out;

    int N = in_sizes[0] / D;   // 50000
    int E = in_sizes[1] / 2;   // 800000
    const int* src = ei;
    const int* dst = ei + E;

    char* w = (char*)d_ws;
    unsigned short* HbA = (unsigned short*)w; w += (size_t)N * DPB * 2;
    unsigned short* HbB = (unsigned short*)w; w += (size_t)N * DPB * 2;
    int* cnt            = (int*)w;            w += (size_t)N * 4;
    unsigned short* earr= (unsigned short*)w; w += (size_t)N * CAP * 2;
    int* gstart         = (int*)w;            w += (size_t)(NGRAPH + 1) * 4;
    unsigned short* WT1 = (unsigned short*)w; w += (size_t)144 * KS * 2;
    unsigned short* WT2 = (unsigned short*)w; w += (size_t)144 * KS * 2;

    int wtB = (144 * KS + 255) / 256;      // 95
    int czB = (N + 255) / 256;             // 196
    int gsB = (NGRAPH + 1 + 255) / 256;    // 2

    int mt = (N + 15) / 16;                // 3125 M-tiles
    int mmB = (mt + 3) / 4;                // 782 mm1 blocks (4 tiles each)
    int chunks = (E + 256 * EU - 1) / (256 * EU);  // 391 edge windows
    int nfill = 8 * chunks;                // 3128 fill blocks (%8 = dst range)
    int grid_agg = (N * NCGB + 255) / 256;

    k_wt    <<<2 * wtB + czB + gsB, 256, 0, stream>>>(W1, WT1, W2, WT2, cnt,
                                                      batch, gstart, N, wtB, czB);
    k_big   <<<nfill + mmB, 256, 0, stream>>>(x, WT1, HbA, src, dst, cnt, earr,
                                              N, E, mt, nfill);
    k_aggmm <<<mt, 320, 0, stream>>>(HbA, b1, cnt, earr, WT2, HbB, N);
    k_agg2  <<<grid_agg, 256, 0, stream>>>(HbB, b2, cnt, earr, HbA, N);
    k_pool  <<<NGRAPH * NCGB, 256, 0, stream>>>(HbA, gstart, out);
}

// Round 13
// 244.919 us; speedup vs baseline: 1.0569x; 1.0569x over previous
//
#include <hip/hip_runtime.h>

#define D 133
#define DPB 136       // bf16 row stride (ushorts): 272 B = 17x16B; minimal 5-line rows
#define NCGB 17       // bf16 column groups of 8 (covers 136)
#define NGRAPH 256
#define KS 168        // W^T global row stride in ushorts (16B-aligned rows)
#define LSTR 168      // LDS A-tile row stride in ushorts (336 B -> spread banks)
#define NT 9          // N-tiles of 16 (covers 144 >= 133; tile 8 stores only cols<136)
#define CAP 64        // fixed CSR bucket capacity (P(Poisson(16) > 64) ~ 1e-19)

typedef short short8 __attribute__((ext_vector_type(8)));
typedef float float4v __attribute__((ext_vector_type(4)));

__device__ __forceinline__ unsigned short f2bf(float x) {   // RNE
    unsigned int u = __float_as_uint(x);
    u += 0x7fffu + ((u >> 16) & 1u);
    return (unsigned short)(u >> 16);
}

__device__ __forceinline__ void cvt8(uint4 v, float* f) {
    f[0] = __uint_as_float(v.x << 16);
    f[1] = __uint_as_float(v.x & 0xffff0000u);
    f[2] = __uint_as_float(v.y << 16);
    f[3] = __uint_as_float(v.y & 0xffff0000u);
    f[4] = __uint_as_float(v.z << 16);
    f[5] = __uint_as_float(v.z & 0xffff0000u);
    f[6] = __uint_as_float(v.w << 16);
    f[7] = __uint_as_float(v.w & 0xffff0000u);
}

// ---------- prep: wt1 | wt2 | cnt-zero | gstart ----------
__global__ __launch_bounds__(256) void k_wt(const float* __restrict__ W1,
                                            unsigned short* __restrict__ WT1,
                                            const float* __restrict__ W2,
                                            unsigned short* __restrict__ WT2,
                                            int* __restrict__ cnt,
                                            const int* __restrict__ batch,
                                            int* __restrict__ gstart,
                                            int N, int wtB, int czB) {
    int bid = blockIdx.x, t = threadIdx.x;
    if (bid < 2 * wtB) {
        const float* W = (bid < wtB) ? W1 : W2;
        unsigned short* WT = (bid < wtB) ? WT1 : WT2;
        int lb = (bid < wtB) ? bid : bid - wtB;
        int i = lb * 256 + t;
        if (i < 144 * KS) {
            int n = i / KS, k = i - n * KS;
            WT[i] = (n < D && k < D) ? f2bf(W[(size_t)k * D + n]) : (unsigned short)0;
        }
        return;
    }
    bid -= 2 * wtB;
    if (bid < czB) {
        int i = bid * 256 + t;
        if (i < N) cnt[i] = 0;
        return;
    }
    bid -= czB;
    {
        int g = bid * 256 + t;
        if (g > NGRAPH) return;
        int lo = 0, hi = N;
        while (lo < hi) {
            int mid = (lo + hi) >> 1;
            if (batch[mid] < g) lo = mid + 1; else hi = mid;
        }
        gstart[g] = lo;
    }
}

// ---------- fused: edge fill (count+scatter) INTERLEAVED with layer-1 MFMA ----------
// Block pattern within groups of 5: [fill, fill, fill, fill, mm1].
__global__ __launch_bounds__(256, 2) void k_big(const float* __restrict__ X,
                                                const unsigned short* __restrict__ WTg,
                                                unsigned short* __restrict__ Y,
                                                const int* __restrict__ src,
                                                const int* __restrict__ dst,
                                                int* __restrict__ cnt,
                                                unsigned short* __restrict__ earr,
                                                int N, int E, int mt) {
    int bid = blockIdx.x, t = threadIdx.x;
    int g = bid / 5, pos = bid - g * 5;
    if (pos != 4) {                              // --- fill: count + scatter ---
        int i = (g * 4 + pos) * 256 + t;
        if (i < E) {
            int s = src[i];
            int dnode = dst[i];
            int slot = atomicAdd(&cnt[dnode], 1);
            if (slot < CAP) earr[(size_t)dnode * CAP + slot] = (unsigned short)s;
        }
        return;
    }
    // --- mm1: one 16-row tile per wave, fp32 X, cvt in-register ---
    int wave = t >> 6, lane = t & 63;
    int ln16 = lane & 15, quad = lane >> 4;
    int tile = g * 4 + wave;
    if (tile >= mt) return;
    int row0 = tile * 16;
    int ra = row0 + ln16; if (ra > N - 1) ra = N - 1;
    const float* Xr = X + (size_t)ra * D;
    const unsigned short* Wr = WTg + (size_t)ln16 * KS + quad * 8;

    float4v acc[NT];
    #pragma unroll
    for (int n = 0; n < NT; ++n) acc[n] = {0.f, 0.f, 0.f, 0.f};

    #pragma unroll
    for (int kk = 0; kk < 5; ++kk) {
        int cbase = kk * 32 + quad * 8;
        short8 a;
        if (kk < 4) {
            #pragma unroll
            for (int j = 0; j < 8; ++j) a[j] = (short)f2bf(Xr[cbase + j]);
        } else {
            #pragma unroll
            for (int j = 0; j < 8; ++j) {
                int c = cbase + j;
                a[j] = (short)((c < D) ? f2bf(Xr[c]) : 0);
            }
        }
        #pragma unroll
        for (int n = 0; n < NT; ++n) {
            short8 b = *(const short8*)(Wr + n * 16 * KS + kk * 32);
            acc[n] = __builtin_amdgcn_mfma_f32_16x16x32_bf16(a, b, acc[n], 0, 0, 0);
        }
    }
    #pragma unroll
    for (int r = 0; r < 4; ++r) {
        int row = row0 + quad * 4 + r;
        if (row < N) {
            unsigned short* Yr = Y + (size_t)row * DPB + ln16;
            #pragma unroll
            for (int n = 0; n < NT; ++n)
                if (n < 8 || ln16 < 8) Yr[n * 16] = f2bf(acc[n][r]);  // cols < 136
        }
    }
}

// ---------- fused agg1 (gather+norm+bias+relu -> LDS) + mm2 (LDS -> H2) ----------
__global__ __launch_bounds__(320, 2) void k_aggmm(const unsigned short* __restrict__ H,
                                                  const float* __restrict__ bias,
                                                  const int* __restrict__ cnt,
                                                  const unsigned short* __restrict__ earr,
                                                  const unsigned short* __restrict__ WTg,
                                                  unsigned short* __restrict__ Y, int N) {
    __shared__ unsigned short T[16 * LSTR];   // 5.25 KB bf16 A-tile
    int t = threadIdx.x;
    int row0 = blockIdx.x * 16;
    if (t < 272) {                            // --- agg task: node row0+l, col-group cg ---
        int l = t / NCGB;
        int cg = t - l * NCGB;
        int node = row0 + l;
        if (node >= N) node = N - 1;
        int c = cg << 3;
        int degraw = cnt[node];
        float di = rsqrtf((float)(degraw + 1));
        float acc[8], f[8];
        uint4 hv = *(const uint4*)(H + (size_t)node * DPB + c);
        cvt8(hv, f);
        #pragma unroll
        for (int j = 0; j < 8; ++j) acc[j] = di * f[j];
        int deg = degraw > CAP ? CAP : degraw;
        const unsigned short* ep = earr + (size_t)node * CAP;
        int e = 0;
        for (; e + 4 <= deg; e += 4) {
            int s0 = ep[e], s1 = ep[e+1], s2 = ep[e+2], s3 = ep[e+3];
            float w0 = rsqrtf((float)(cnt[s0] + 1));
            float w1 = rsqrtf((float)(cnt[s1] + 1));
            float w2 = rsqrtf((float)(cnt[s2] + 1));
            float w3 = rsqrtf((float)(cnt[s3] + 1));
            uint4 v0 = *(const uint4*)(H + (size_t)s0 * DPB + c);
            uint4 v1 = *(const uint4*)(H + (size_t)s1 * DPB + c);
            uint4 v2 = *(const uint4*)(H + (size_t)s2 * DPB + c);
            uint4 v3 = *(const uint4*)(H + (size_t)s3 * DPB + c);
            cvt8(v0, f);
            #pragma unroll
            for (int j = 0; j < 8; ++j) acc[j] = fmaf(w0, f[j], acc[j]);
            cvt8(v1, f);
            #pragma unroll
            for (int j = 0; j < 8; ++j) acc[j] = fmaf(w1, f[j], acc[j]);
            cvt8(v2, f);
            #pragma unroll
            for (int j = 0; j < 8; ++j) acc[j] = fmaf(w2, f[j], acc[j]);
            cvt8(v3, f);
            #pragma unroll
            for (int j = 0; j < 8; ++j) acc[j] = fmaf(w3, f[j], acc[j]);
        }
        for (; e < deg; ++e) {
            int s = ep[e];
            float wv = rsqrtf((float)(cnt[s] + 1));
            uint4 v = *(const uint4*)(H + (size_t)s * DPB + c);
            cvt8(v, f);
            #pragma unroll
            for (int j = 0; j < 8; ++j) acc[j] = fmaf(wv, f[j], acc[j]);
        }
        float b[8];
        #pragma unroll
        for (int j = 0; j < 8; ++j) b[j] = (c + j < D) ? bias[c + j] : 0.f;
        unsigned int p[4];
        #pragma unroll
        for (int j = 0; j < 4; ++j) {
            float lo = fmaxf(fmaf(di, acc[2*j],   b[2*j]),   0.f);
            float hi = fmaxf(fmaf(di, acc[2*j+1], b[2*j+1]), 0.f);
            p[j] = (unsigned int)f2bf(lo) | ((unsigned int)f2bf(hi) << 16);
        }
        uint4 pk = {p[0], p[1], p[2], p[3]};
        *(uint4*)(T + l * LSTR + c) = pk;
    } else {                                  // --- zero LDS K-pads 136..159 ---
        int k = t - 272;
        int l = k / 3, seg = k - l * 3;
        uint4 z = {0u, 0u, 0u, 0u};
        *(uint4*)(T + l * LSTR + 136 + seg * 8) = z;
    }
    __syncthreads();

    // --- mm2: 5 waves split the 9 N-tiles; A-frags from LDS ---
    int wave = t >> 6, lane = t & 63;
    int ln16 = lane & 15, quad = lane >> 4;
    const unsigned short* Ar = T + ln16 * LSTR + quad * 8;
    const unsigned short* Wr = WTg + (size_t)ln16 * KS + quad * 8;
    for (int n = wave; n < NT; n += 5) {
        float4v acc2 = {0.f, 0.f, 0.f, 0.f};
        #pragma unroll
        for (int kk = 0; kk < 5; ++kk) {
            short8 a = *(const short8*)(Ar + kk * 32);
            short8 b = *(const short8*)(Wr + n * 16 * KS + kk * 32);
            acc2 = __builtin_amdgcn_mfma_f32_16x16x32_bf16(a, b, acc2, 0, 0, 0);
        }
        if (n < 8 || ln16 < 8) {              // cols < 136 only
            #pragma unroll
            for (int r = 0; r < 4; ++r) {
                int row = row0 + quad * 4 + r;
                if (row < N) Y[(size_t)row * DPB + n * 16 + ln16] = f2bf(acc2[r]);
            }
        }
    }
}

// ---------- agg2: gather+norm+bias+relu; bf16 out ----------
__global__ __launch_bounds__(256) void k_agg2(const unsigned short* __restrict__ H,
                                              const float* __restrict__ bias,
                                              const int* __restrict__ cnt,
                                              const unsigned short* __restrict__ earr,
                                              unsigned short* __restrict__ outb, int N) {
    int idx = blockIdx.x * 256 + threadIdx.x;
    if (idx >= N * NCGB) return;
    int node = idx / NCGB;
    int cg = idx - node * NCGB;
    int c = cg << 3;
    int degraw = cnt[node];
    float di = rsqrtf((float)(degraw + 1));
    float acc[8], f[8];
    uint4 hv = *(const uint4*)(H + (size_t)node * DPB + c);
    cvt8(hv, f);
    #pragma unroll
    for (int j = 0; j < 8; ++j) acc[j] = di * f[j];
    int deg = degraw > CAP ? CAP : degraw;
    const unsigned short* ep = earr + (size_t)node * CAP;
    int e = 0;
    for (; e + 4 <= deg; e += 4) {
        int s0 = ep[e], s1 = ep[e+1], s2 = ep[e+2], s3 = ep[e+3];
        float w0 = rsqrtf((float)(cnt[s0] + 1));
        float w1 = rsqrtf((float)(cnt[s1] + 1));
        float w2 = rsqrtf((float)(cnt[s2] + 1));
        float w3 = rsqrtf((float)(cnt[s3] + 1));
        uint4 v0 = *(const uint4*)(H + (size_t)s0 * DPB + c);
        uint4 v1 = *(const uint4*)(H + (size_t)s1 * DPB + c);
        uint4 v2 = *(const uint4*)(H + (size_t)s2 * DPB + c);
        uint4 v3 = *(const uint4*)(H + (size_t)s3 * DPB + c);
        cvt8(v0, f);
        #pragma unroll
        for (int j = 0; j < 8; ++j) acc[j] = fmaf(w0, f[j], acc[j]);
        cvt8(v1, f);
        #pragma unroll
        for (int j = 0; j < 8; ++j) acc[j] = fmaf(w1, f[j], acc[j]);
        cvt8(v2, f);
        #pragma unroll
        for (int j = 0; j < 8; ++j) acc[j] = fmaf(w2, f[j], acc[j]);
        cvt8(v3, f);
        #pragma unroll
        for (int j = 0; j < 8; ++j) acc[j] = fmaf(w3, f[j], acc[j]);
    }
    for (; e < deg; ++e) {
        int s = ep[e];
        float wv = rsqrtf((float)(cnt[s] + 1));
        uint4 v = *(const uint4*)(H + (size_t)s * DPB + c);
        cvt8(v, f);
        #pragma unroll
        for (int j = 0; j < 8; ++j) acc[j] = fmaf(wv, f[j], acc[j]);
    }
    float b[8];
    #pragma unroll
    for (int j = 0; j < 8; ++j) b[j] = (c + j < D) ? bias[c + j] : 0.f;
    unsigned int p[4];
    #pragma unroll
    for (int j = 0; j < 4; ++j) {
        float lo = fmaxf(fmaf(di, acc[2*j],   b[2*j]),   0.f);
        float hi = fmaxf(fmaf(di, acc[2*j+1], b[2*j+1]), 0.f);
        p[j] = (unsigned int)f2bf(lo) | ((unsigned int)f2bf(hi) << 16);
    }
    uint4 pk = {p[0], p[1], p[2], p[3]};
    *(uint4*)(outb + (size_t)node * DPB + c) = pk;
}

// ---------- per-graph mean pool: one block per (graph, col-group of 8) ----------
__global__ __launch_bounds__(256) void k_pool(const unsigned short* __restrict__ H,
                                              const int* __restrict__ gstart,
                                              float* __restrict__ out) {
    int g = blockIdx.x / NCGB;
    int cg = blockIdx.x - g * NCGB;
    int c = cg << 3;
    int t = threadIdx.x;
    int s = gstart[g], e = gstart[g + 1];
    float acc[8], f[8];
    #pragma unroll
    for (int j = 0; j < 8; ++j) acc[j] = 0.f;
    for (int i = s + t; i < e; i += 256) {
        uint4 v = *(const uint4*)(H + (size_t)i * DPB + c);
        cvt8(v, f);
        #pragma unroll
        for (int j = 0; j < 8; ++j) acc[j] += f[j];
    }
    #pragma unroll
    for (int off = 32; off >= 1; off >>= 1) {
        #pragma unroll
        for (int j = 0; j < 8; ++j) acc[j] += __shfl_down(acc[j], off, 64);
    }
    __shared__ float part[4][8];
    int wave = t >> 6, lane = t & 63;
    if (lane == 0) {
        #pragma unroll
        for (int j = 0; j < 8; ++j) part[wave][j] = acc[j];
    }
    __syncthreads();
    if (t < 8) {
        int col = c + t;
        if (col < D) {
            float v = part[0][t] + part[1][t] + part[2][t] + part[3][t];
            float n = (float)(e - s);
            out[(size_t)g * D + col] = v / fmaxf(n, 1.f);
        }
    }
}

extern "C" void kernel_launch(void* const* d_in, const int* in_sizes, int n_in,
                              void* d_out, int out_size, void* d_ws, size_t ws_size,
                              hipStream_t stream) {
    const float* x   = (const float*)d_in[0];
    const int* ei    = (const int*)d_in[1];
    const int* batch = (const int*)d_in[2];
    const float* W1  = (const float*)d_in[3];
    const float* b1  = (const float*)d_in[4];
    const float* W2  = (const float*)d_in[5];
    const float* b2  = (const float*)d_in[6];
    float* out = (float*)d_out;

    int N = in_sizes[0] / D;   // 50000
    int E = in_sizes[1] / 2;   // 800000
    const int* src = ei;
    const int* dst = ei + E;

    char* w = (char*)d_ws;
    unsigned short* HbA = (unsigned short*)w; w += (size_t)N * DPB * 2;
    unsigned short* HbB = (unsigned short*)w; w += (size_t)N * DPB * 2;
    int* cnt            = (int*)w;            w += (size_t)N * 4;
    unsigned short* earr= (unsigned short*)w; w += (size_t)N * CAP * 2;
    int* gstart         = (int*)w;            w += (size_t)(NGRAPH + 1) * 4;
    unsigned short* WT1 = (unsigned short*)w; w += (size_t)144 * KS * 2;
    unsigned short* WT2 = (unsigned short*)w; w += (size_t)144 * KS * 2;

    int wtB = (144 * KS + 255) / 256;      // 95
    int czB = (N + 255) / 256;             // 196
    int gsB = (NGRAPH + 1 + 255) / 256;    // 2

    int mt = (N + 15) / 16;                // 3125 M-tiles
    int mmB = (mt + 3) / 4;                // 782 mm1 groups (4 tiles each)
    int nib = 5 * mmB;                     // interleaved: 4 fill + 1 mm per group
    int grid_agg = (N * NCGB + 255) / 256;

    k_wt    <<<2 * wtB + czB + gsB, 256, 0, stream>>>(W1, WT1, W2, WT2, cnt,
                                                      batch, gstart, N, wtB, czB);
    k_big   <<<nib, 256, 0, stream>>>(x, WT1, HbA, src, dst, cnt, earr, N, E, mt);
    k_aggmm <<<mt, 320, 0, stream>>>(HbA, b1, cnt, earr, WT2, HbB, N);
    k_agg2  <<<grid_agg, 256, 0, stream>>>(HbB, b2, cnt, earr, HbA, N);
    k_pool  <<<NGRAPH * NCGB, 256, 0, stream>>>(HbA, gstart, out);
}